// Round 14
// baseline (27.086 us; speedup 1.0000x reference)
//
#include <hip/hip_runtime.h>
#include <hip/hip_fp16.h>

// Joint bilateral filter, K=5, zero padding. R12/R13 body + CROSS-TILE PREFETCH:
// persistent 1280 blocks (5/CU residency), XCD band swizzle, and the next
// tile's 8 global float4 loads issued BEFORE the current tile's compute.
// The vmcnt wait lands at the first use (ds_write after compute), so global
// latency hides under the ~2200-cycle tap loop. LDS stays single-buffered.
// t: (2,3,720,1280) f32; v: (2,2,720,1280) f32; out: (2,2,720,1280) f32
// coeff = max(0.875 - 50*sum_c (t_c - ts_c)^2, 0); out = sum(vs*coeff)/sum(coeff)

constexpr int H_ = 720;
constexpr int W_ = 1280;
constexpr int HW = H_ * W_;
constexpr float COEF0 = 0.875f;  // 1 - |NEG_SS_DIV|
constexpr float SIDIV = 50.0f;   // 1/(2*0.1^2)

constexpr int TC = 132;          // staged cols: global gx0-2 .. gx0+129
constexpr int TR = 12;           // staged rows: gy0-2 .. gy0+9
constexpr int NK = 34;           // aligned global chunks per row (gx0-4+4k)
constexpr int NCHUNK = 5 * TR * NK;   // 2040
constexpr int NXCD = 8;
constexpr int NTILES = 1800;
constexpr int GRID = 1280;       // 5 blocks/CU * 256 CUs; 1280 % 8 == 0
constexpr int CPX = NTILES / NXCD;    // 225 tiles per XCD band

__device__ __forceinline__ void decode_tile(int vid, int& n, int& gx0, int& gy0) {
    // XCD-aware bijective swizzle: XCD i owns tiles [i*225, (i+1)*225).
    // Block b's tiles are vid=b and vid=b+1280; (b&7)==((b+1280)&7) -> same band.
    const int wgid = (vid & (NXCD - 1)) * CPX + (vid >> 3);
    n = wgid / 900;
    const int rem = wgid % 900;
    gy0 = (rem / 10) * 8;
    gx0 = (rem % 10) * 128;
}

__device__ __forceinline__ void load_tile(const float* __restrict__ t,
                                          const float* __restrict__ v,
                                          int n, int gx0, int gy0, int tid,
                                          float4 (&vals)[8]) {
    const float* tn = t + (size_t)n * 3 * HW;
    const float* vn = v + (size_t)n * 2 * HW;
#pragma unroll
    for (int it = 0; it < 8; ++it) {
        const int i = tid + it * 256;    // it<7 always < NCHUNK; it==7 guarded
        const int k  = i % NK;
        const int rr = (i / NK) % TR;
        const int ch = i / (NK * TR);
        const int gy = gy0 - 2 + rr;
        const int gx = gx0 - 4 + 4 * k;
        vals[it] = make_float4(0.f, 0.f, 0.f, 0.f);
        const bool live = (it < 7 || i < NCHUNK) &&
                          ((unsigned)gy < (unsigned)H_) &&
                          ((unsigned)gx < (unsigned)(W_ - 3));
        if (live) {
            const float* src = (ch < 3) ? (tn + (size_t)ch * HW)
                                        : (vn + (size_t)(ch - 3) * HW);
            vals[it] = *(const float4*)(src + gy * W_ + gx);  // 8 independent loads
        }
    }
}

__device__ __forceinline__ void write_tile(float (*lds)[TR][TC], int tid,
                                           const float4 (&vals)[8]) {
#pragma unroll
    for (int it = 0; it < 8; ++it) {
        const int i = tid + it * 256;
        if (it < 7 || i < NCHUNK) {
            const int k  = i % NK;
            const int rr = (i / NK) % TR;
            const int ch = i / (NK * TR);
            // global cols gx..gx+3 <-> staged cols 4k-2 .. 4k+1
            float* row = &lds[ch][rr][0];
            const float4 val = vals[it];
            if (k > 0)      *(float2*)&row[4 * k - 2] = make_float2(val.x, val.y);
            if (k < NK - 1) *(float2*)&row[4 * k]     = make_float2(val.z, val.w);
        }
    }
}

// load one staged row's 8-wide windows (5 channels) into FRESH arrays in scope
#define LOADW(LR)                                                              \
    float w0[8], w1[8], w2[8], u0[8], u1[8];                                   \
    _Pragma("unroll") for (int s_ = 0; s_ < 2; ++s_) {                         \
        *(float4*)(w0 + 4 * s_) = *(const float4*)&lds[0][LR][lc + 4 * s_];    \
        *(float4*)(w1 + 4 * s_) = *(const float4*)&lds[1][LR][lc + 4 * s_];    \
        *(float4*)(w2 + 4 * s_) = *(const float4*)&lds[2][LR][lc + 4 * s_];    \
        *(float4*)(u0 + 4 * s_) = *(const float4*)&lds[3][LR][lc + 4 * s_];    \
        *(float4*)(u1 + 4 * s_) = *(const float4*)&lds[4][LR][lc + 4 * s_];    \
    }

// accumulate 5x4 taps; tap k = dx+j in [0,7]
#define COMPW()                                                                \
    _Pragma("unroll") for (int dx_ = 0; dx_ < 5; ++dx_)                        \
        _Pragma("unroll") for (int j_ = 0; j_ < 4; ++j_) {                     \
            const int k_ = dx_ + j_;                                           \
            const float d0_ = c0f[j_] - w0[k_];                                \
            const float d1_ = c1f[j_] - w1[k_];                                \
            const float d2_ = c2f[j_] - w2[k_];                                \
            float diff_ = d0_ * d0_;                                           \
            diff_ = fmaf(d1_, d1_, diff_);                                     \
            diff_ = fmaf(d2_, d2_, diff_);                                     \
            const float c_ = fmaxf(fmaf(diff_, -SIDIV, COEF0), 0.f);           \
            num0[j_] = fmaf(u0[k_], c_, num0[j_]);                             \
            num1[j_] = fmaf(u1[k_], c_, num1[j_]);                             \
            den[j_] += c_;                                                     \
        }

__device__ __forceinline__ void compute_store(const float (*lds)[TR][TC],
                                              float* __restrict__ out,
                                              int n, int gx0, int gy0, int tid) {
    float* on = out + (size_t)n * 2 * HW;
    const int tx = tid & 31;
    const int ty = tid >> 5;
    const int lc = 4 * tx;

    float c0f[4], c1f[4], c2f[4];
    float num0[4] = {0.f, 0.f, 0.f, 0.f};
    float num1[4] = {0.f, 0.f, 0.f, 0.f};
    float den[4]  = {0.f, 0.f, 0.f, 0.f};

    {   // r = 2 first: its window contains the centers (elem j+2 = pixel j)
        const int lr = ty + 2;
        LOADW(lr)
#pragma unroll
        for (int j = 0; j < 4; ++j) {
            c0f[j] = w0[j + 2];
            c1f[j] = w1[j + 2];
            c2f[j] = w2[j + 2];
        }
        COMPW()
    }
#pragma unroll 1
    for (int i = 0; i < 4; ++i) {
        const int r = i + (i >> 1);          // 0,1,3,4
        const int lr = ty + r;
        LOADW(lr)
        COMPW()
    }

    float4 o0, o1;
    float* o0a = (float*)&o0;
    float* o1a = (float*)&o1;
#pragma unroll
    for (int j = 0; j < 4; ++j) {
        const float rcp = 1.f / den[j];
        // mimic the reference's fp16 round-trip
        o0a[j] = __half2float(__float2half(num0[j] * rcp));
        o1a[j] = __half2float(__float2half(num1[j] * rcp));
    }
    const int ctr = (gy0 + ty) * W_ + gx0 + 4 * tx;
    *(float4*)(on + ctr) = o0;
    *(float4*)(on + HW + ctr) = o1;
}

__global__ __launch_bounds__(256)
void jbf_pp(const float* __restrict__ t, const float* __restrict__ v,
            float* __restrict__ out) {
    __shared__ float lds[5][TR][TC];        // 31,680 B -> 5 blocks/CU

    const int tid = threadIdx.x;
    const bool two = ((int)blockIdx.x < NTILES - GRID);   // first 520 blocks: 2 tiles

    int nA, gxA, gyA;
    decode_tile(blockIdx.x, nA, gxA, gyA);

    float4 vals[8];
    load_tile(t, v, nA, gxA, gyA, tid, vals);
    write_tile(lds, tid, vals);             // vmcnt waits here (prologue only)
    __syncthreads();

    if (two) {
        int nB, gxB, gyB;
        decode_tile((int)blockIdx.x + GRID, nB, gxB, gyB);
        // prefetch tile B: loads in flight across the whole tile-A compute
        load_tile(t, v, nB, gxB, gyB, tid, vals);
        compute_store(lds, out, nA, gxA, gyA, tid);
        __syncthreads();                    // all waves done reading tile A
        write_tile(lds, tid, vals);         // first use of B's loads -> vmcnt here
        __syncthreads();
        compute_store(lds, out, nB, gxB, gyB, tid);
    } else {
        compute_store(lds, out, nA, gxA, gyA, tid);
    }
}

extern "C" void kernel_launch(void* const* d_in, const int* in_sizes, int n_in,
                              void* d_out, int out_size, void* d_ws, size_t ws_size,
                              hipStream_t stream) {
    const float* t = (const float*)d_in[0];
    const float* v = (const float*)d_in[1];
    float* out = (float*)d_out;

    // persistent: 1280 blocks (5/CU), first 520 take a second tile (+1280, same XCD band)
    jbf_pp<<<GRID, 256, 0, stream>>>(t, v, out);
}

// Round 15
// 26.443 us; speedup vs baseline: 1.0243x; 1.0243x over previous
//
#include <hip/hip_runtime.h>
#include <hip/hip_fp16.h>

// Joint bilateral filter, K=5, zero padding. R13 (shifted LDS layout, XCD band
// swizzle, reg-staged MLP loads, best 26.5us) + WAVE/BLOCK ROW DE-PHASING:
// after the center row, each wave visits the remaining 4 rows in an order
// rotated by ((tid>>6)+(blockIdx>>3))&3. Breaks the lockstep convoys
// (all waves bursting LOADW together then computing together) that cap
// VALUBusy at ~38% while every pipe sits <35% utilized.
// t: (2,3,720,1280) f32; v: (2,2,720,1280) f32; out: (2,2,720,1280) f32
// coeff = max(0.875 - 50*sum_c (t_c - ts_c)^2, 0); out = sum(vs*coeff)/sum(coeff)

constexpr int H_ = 720;
constexpr int W_ = 1280;
constexpr int HW = H_ * W_;
constexpr float COEF0 = 0.875f;  // 1 - |NEG_SS_DIV|
constexpr float SIDIV = 50.0f;   // 1/(2*0.1^2)

constexpr int TC = 132;          // staged cols: global gx0-2 .. gx0+129
constexpr int TR = 12;           // staged rows: gy0-2 .. gy0+9
constexpr int NK = 34;           // aligned global chunks per row (gx0-4+4k)
constexpr int NCHUNK = 5 * TR * NK;   // 2040
constexpr int NXCD = 8;
constexpr int CPX = 1800 / NXCD; // 225 tiles per XCD band (exact)

// load one staged row's 8-wide windows (5 channels) into FRESH arrays in scope
#define LOADW(LR)                                                              \
    float w0[8], w1[8], w2[8], u0[8], u1[8];                                   \
    _Pragma("unroll") for (int s_ = 0; s_ < 2; ++s_) {                         \
        *(float4*)(w0 + 4 * s_) = *(const float4*)&lds[0][LR][lc + 4 * s_];    \
        *(float4*)(w1 + 4 * s_) = *(const float4*)&lds[1][LR][lc + 4 * s_];    \
        *(float4*)(w2 + 4 * s_) = *(const float4*)&lds[2][LR][lc + 4 * s_];    \
        *(float4*)(u0 + 4 * s_) = *(const float4*)&lds[3][LR][lc + 4 * s_];    \
        *(float4*)(u1 + 4 * s_) = *(const float4*)&lds[4][LR][lc + 4 * s_];    \
    }

// accumulate 5x4 taps; window elem m <-> global col x0w+m, tap k = dx+j in [0,7]
#define COMPW()                                                                \
    _Pragma("unroll") for (int dx_ = 0; dx_ < 5; ++dx_)                        \
        _Pragma("unroll") for (int j_ = 0; j_ < 4; ++j_) {                     \
            const int k_ = dx_ + j_;                                           \
            const float d0_ = c0f[j_] - w0[k_];                                \
            const float d1_ = c1f[j_] - w1[k_];                                \
            const float d2_ = c2f[j_] - w2[k_];                                \
            float diff_ = d0_ * d0_;                                           \
            diff_ = fmaf(d1_, d1_, diff_);                                     \
            diff_ = fmaf(d2_, d2_, diff_);                                     \
            const float c_ = fmaxf(fmaf(diff_, -SIDIV, COEF0), 0.f);           \
            num0[j_] = fmaf(u0[k_], c_, num0[j_]);                             \
            num1[j_] = fmaf(u1[k_], c_, num1[j_]);                             \
            den[j_] += c_;                                                     \
        }

__global__ __launch_bounds__(256)
void jbf_dp(const float* __restrict__ t, const float* __restrict__ v,
            float* __restrict__ out) {
    __shared__ float lds[5][TR][TC];        // 31,680 B -> 5 blocks/CU

    // ---- XCD-aware bijective swizzle: XCD i owns tiles [i*225, (i+1)*225) ----
    const int wgid = (blockIdx.x & (NXCD - 1)) * CPX + (blockIdx.x >> 3);
    const int n   = wgid / 900;             // image
    const int rem = wgid % 900;
    const int by  = rem / 10;               // tile-row (y-major band)
    const int bx  = rem % 10;
    const int gx0 = bx * 128;
    const int gy0 = by * 8;

    const float* tn = t + (size_t)n * 3 * HW;
    const float* vn = v + (size_t)n * 2 * HW;
    float*       on = out + (size_t)n * 2 * HW;

    const int tid = threadIdx.x;

    // ---------------- stage, phase 1: issue ALL global loads ----------------
    float4 vals[8];
#pragma unroll
    for (int it = 0; it < 8; ++it) {
        const int i = tid + it * 256;       // it<7 always < NCHUNK; it==7 guarded
        const int k  = i % NK;
        const int rr = (i / NK) % TR;
        const int ch = i / (NK * TR);
        const int gy = gy0 - 2 + rr;
        const int gx = gx0 - 4 + 4 * k;
        vals[it] = make_float4(0.f, 0.f, 0.f, 0.f);
        const bool live = (it < 7 || i < NCHUNK) &&
                          ((unsigned)gy < (unsigned)H_) &&
                          ((unsigned)gx < (unsigned)(W_ - 3));
        if (live) {
            const float* src = (ch < 3) ? (tn + (size_t)ch * HW)
                                        : (vn + (size_t)(ch - 3) * HW);
            vals[it] = *(const float4*)(src + gy * W_ + gx);   // 8 independent loads
        }
    }

    // ---------------- stage, phase 2: all LDS writes ----------------
#pragma unroll
    for (int it = 0; it < 8; ++it) {
        const int i = tid + it * 256;
        if (it < 7 || i < NCHUNK) {
            const int k  = i % NK;
            const int rr = (i / NK) % TR;
            const int ch = i / (NK * TR);
            // global cols gx..gx+3 <-> staged cols 4k-2 .. 4k+1
            float* row = &lds[ch][rr][0];
            const float4 val = vals[it];
            if (k > 0)      *(float2*)&row[4 * k - 2] = make_float2(val.x, val.y);
            if (k < NK - 1) *(float2*)&row[4 * k]     = make_float2(val.z, val.w);
        }
    }
    __syncthreads();

    // ---------------- compute 4 px from LDS, de-phased row order ----------------
    const int tx = tid & 31;                 // x-group within tile
    const int ty = tid >> 5;                 // output row within tile
    const int lc = 4 * tx;                   // window base staged col
    const int rot = ((tid >> 6) + ((int)blockIdx.x >> 3)) & 3;  // wave+block stagger

    float c0f[4], c1f[4], c2f[4];
    float num0[4] = {0.f, 0.f, 0.f, 0.f};
    float num1[4] = {0.f, 0.f, 0.f, 0.f};
    float den[4]  = {0.f, 0.f, 0.f, 0.f};

    {   // r = 2 first: its window contains the centers (elem j+2 = pixel j)
        const int lr = ty + 2;
        LOADW(lr)
#pragma unroll
        for (int j = 0; j < 4; ++j) {
            c0f[j] = w0[j + 2];
            c1f[j] = w1[j + 2];
            c2f[j] = w2[j + 2];
        }
        COMPW()
    }
#pragma unroll 1
    for (int i = 0; i < 4; ++i) {
        const int m = (i + rot) & 3;         // rotated visit order per wave/block
        const int r = m + (m >> 1);          // {0,1,3,4}
        const int lr = ty + r;
        LOADW(lr)
        COMPW()
    }

    float4 o0, o1;
    float* o0a = (float*)&o0;
    float* o1a = (float*)&o1;
#pragma unroll
    for (int j = 0; j < 4; ++j) {
        const float rcp = 1.f / den[j];
        // mimic the reference's fp16 round-trip
        o0a[j] = __half2float(__float2half(num0[j] * rcp));
        o1a[j] = __half2float(__float2half(num1[j] * rcp));
    }
    const int ctr = (gy0 + ty) * W_ + gx0 + 4 * tx;
    *(float4*)(on + ctr) = o0;
    *(float4*)(on + HW + ctr) = o1;
}

extern "C" void kernel_launch(void* const* d_in, const int* in_sizes, int n_in,
                              void* d_out, int out_size, void* d_ws, size_t ws_size,
                              hipStream_t stream) {
    const float* t = (const float*)d_in[0];
    const float* v = (const float*)d_in[1];
    float* out = (float*)d_out;

    // 10 x-tiles * 90 y-tiles * 2 images = 1800 blocks of 256 (XCD-swizzled)
    jbf_dp<<<1800, 256, 0, stream>>>(t, v, out);
}

// Round 17
// 26.082 us; speedup vs baseline: 1.0385x; 1.0138x over previous
//
#include <hip/hip_runtime.h>
#include <hip/hip_fp16.h>

// Joint bilateral filter, K=5, zero padding. fp16 packed LDS + dot2 tap math.
// t: (2,3,720,1280) f32; v: (2,2,720,1280) f32; out: (2,2,720,1280) f32
// coeff = max(0.875 - 50*sum_c (t_c-ts_c)^2, 0); out = sum(vs*coeff)/sum(coeff)
//
// LDS: ldsA=(t0,t1) half2, ldsB=t2 half (row stride 136 for 16B-aligned rows),
// ldsC=(v0,v1) half2; shifted layout (staged col c <-> global gx0-2+c) so each
// thread's 8-px window is aligned reads: 2xb128(A) + 2xb64(B) + 2xb128(C).
// 15.9KB LDS -> 8 blocks/CU (32 waves). Tap: pk_sub + fdot2 + mix-fma ~9 VALU.
// Lessons kept: no launch_bounds min-waves (R6/R9 clamp+spill), reg-staged MLP
// loads (R13), XCD band swizzle (R12), fresh-scope arrays + static idx (R7).
// R16 fix: cvt_pkrtz returns __fp16 vec2 -> bit_cast to _Float16 vec2.

typedef _Float16 f16x2 __attribute__((ext_vector_type(2)));
typedef _Float16 f16x4 __attribute__((ext_vector_type(4)));
typedef _Float16 f16x8 __attribute__((ext_vector_type(8)));

static __device__ __forceinline__ f16x2 pkrtz(float a, float b) {
    return __builtin_bit_cast(f16x2, __builtin_amdgcn_cvt_pkrtz(a, b));
}

constexpr int H_ = 720;
constexpr int W_ = 1280;
constexpr int HW = H_ * W_;
constexpr float COEF0 = 0.875f;
constexpr float SIDIV = 50.0f;

constexpr int TC  = 132;          // staged cols: global gx0-2 .. gx0+129
constexpr int TCB = 136;          // ldsB padded stride (272B rows, 16B aligned)
constexpr int TR  = 12;           // staged rows: gy0-2 .. gy0+9
constexpr int NK  = 34;           // aligned global chunks per row (gx0-4+4k)
constexpr int NITEM = 3 * TR * NK;    // 1224 staging items (t01 / t2 / v01)
constexpr int NXCD = 8;
constexpr int CPX = 1800 / NXCD;

__global__ __launch_bounds__(256)
void jbf_h2(const float* __restrict__ t, const float* __restrict__ v,
            float* __restrict__ out) {
    __shared__ alignas(16) f16x2    ldsA[TR][TC];   // (t0,t1)  6336 B
    __shared__ alignas(16) _Float16 ldsB[TR][TCB];  // t2       3264 B
    __shared__ alignas(16) f16x2    ldsC[TR][TC];   // (v0,v1)  6336 B

    // XCD-aware bijective swizzle: XCD i owns tiles [i*225, (i+1)*225)
    const int wgid = (blockIdx.x & (NXCD - 1)) * CPX + (blockIdx.x >> 3);
    const int n   = wgid / 900;
    const int rem = wgid % 900;
    const int gy0 = (rem / 10) * 8;
    const int gx0 = (rem % 10) * 128;

    const float* tn = t + (size_t)n * 3 * HW;
    const float* vn = v + (size_t)n * 2 * HW;
    float*       on = out + (size_t)n * 2 * HW;

    const int tid = threadIdx.x;

    // ---- stage phase 1: issue all global loads (items: st 0=t01, 1=t2, 2=v01) ----
    float4 pA[5], pB[5];
#pragma unroll
    for (int it = 0; it < 5; ++it) {
        const int i  = tid + it * 256;       // it<4 always < NITEM; it==4 guarded
        const int st = i / 408;
        const int idx = i % 408;
        const int rr = idx / 34, k = idx % 34;
        const int gy = gy0 - 2 + rr;
        const int gx = gx0 - 4 + 4 * k;
        pA[it] = make_float4(0.f, 0.f, 0.f, 0.f);
        pB[it] = make_float4(0.f, 0.f, 0.f, 0.f);
        const bool live = (it < 4 || i < NITEM) &&
                          ((unsigned)gy < (unsigned)H_) &&
                          ((unsigned)gx < (unsigned)(W_ - 3));
        if (live) {
            const float* base = tn + gy * W_ + gx;
            if (st == 0) {
                pA[it] = *(const float4*)(base);
                pB[it] = *(const float4*)(base + HW);
            } else if (st == 1) {
                pA[it] = *(const float4*)(base + 2 * HW);
            } else {
                const float* vb = vn + gy * W_ + gx;
                pA[it] = *(const float4*)(vb);
                pB[it] = *(const float4*)(vb + HW);
            }
        }
    }

    // ---- stage phase 2: convert to fp16 and write LDS (shifted layout) ----
#pragma unroll
    for (int it = 0; it < 5; ++it) {
        const int i = tid + it * 256;
        if (it < 4 || i < NITEM) {
            const int st = i / 408;
            const int idx = i % 408;
            const int rr = idx / 34, k = idx % 34;
            const float4 a = pA[it], b = pB[it];
            if (st == 1) {
                const f16x2 q0 = pkrtz(a.x, a.y);
                const f16x2 q1 = pkrtz(a.z, a.w);
                if (k > 0)      *(f16x2*)&ldsB[rr][4 * k - 2] = q0;
                if (k < NK - 1) *(f16x2*)&ldsB[rr][4 * k]     = q1;
            } else {
                // per-pixel (chA,chB) packed half2
                const f16x2 p0 = pkrtz(a.x, b.x);
                const f16x2 p1 = pkrtz(a.y, b.y);
                const f16x2 p2 = pkrtz(a.z, b.z);
                const f16x2 p3 = pkrtz(a.w, b.w);
                f16x2 (*dst)[TC] = (st == 0) ? ldsA : ldsC;
                if (k > 0) {
                    f16x4 lo = {p0.x, p0.y, p1.x, p1.y};
                    *(f16x4*)&dst[rr][4 * k - 2] = lo;
                }
                if (k < NK - 1) {
                    f16x4 hi = {p2.x, p2.y, p3.x, p3.y};
                    *(f16x4*)&dst[rr][4 * k] = hi;
                }
            }
        }
    }
    __syncthreads();

    // ---------------- compute 4 px ----------------
    const int tx = tid & 31;
    const int ty = tid >> 5;
    const int lc = 4 * tx;                   // window base staged col

    float num0[4] = {0.f, 0.f, 0.f, 0.f};
    float num1[4] = {0.f, 0.f, 0.f, 0.f};
    float den[4]  = {0.f, 0.f, 0.f, 0.f};
    f16x2 c01[4];
    float c2f[4];

#define LOADW(LR)                                                              \
    f16x2 a01[8]; f16x2 uv[8]; float w2f[8];                                   \
    {                                                                          \
        *(f16x8*)&a01[0] = *(const f16x8*)&ldsA[LR][lc];                       \
        *(f16x8*)&a01[4] = *(const f16x8*)&ldsA[LR][lc + 4];                   \
        f16x4 b0 = *(const f16x4*)&ldsB[LR][lc];                               \
        f16x4 b1 = *(const f16x4*)&ldsB[LR][lc + 4];                           \
        *(f16x8*)&uv[0] = *(const f16x8*)&ldsC[LR][lc];                        \
        *(f16x8*)&uv[4] = *(const f16x8*)&ldsC[LR][lc + 4];                    \
        _Pragma("unroll") for (int m_ = 0; m_ < 4; ++m_) {                     \
            w2f[m_]     = (float)b0[m_];                                       \
            w2f[m_ + 4] = (float)b1[m_];                                       \
        }                                                                      \
    }

#define COMPW()                                                                \
    _Pragma("unroll") for (int dx_ = 0; dx_ < 5; ++dx_)                        \
        _Pragma("unroll") for (int j_ = 0; j_ < 4; ++j_) {                     \
            const int k_ = dx_ + j_;                                           \
            const f16x2 d01 = a01[k_] - c01[j_];                               \
            const float d2  = w2f[k_] - c2f[j_];                               \
            const float diff = __builtin_amdgcn_fdot2(d01, d01, d2 * d2, false);\
            const float c_ = fmaxf(fmaf(diff, -SIDIV, COEF0), 0.f);            \
            num0[j_] = fmaf((float)uv[k_].x, c_, num0[j_]);                    \
            num1[j_] = fmaf((float)uv[k_].y, c_, num1[j_]);                    \
            den[j_] += c_;                                                     \
        }

    {   // r = 2 first: its window contains the centers (elem j+2 = pixel j)
        const int lr = ty + 2;
        LOADW(lr)
#pragma unroll
        for (int j = 0; j < 4; ++j) {
            c01[j] = a01[j + 2];
            c2f[j] = w2f[j + 2];
        }
        COMPW()
    }
#pragma unroll 1
    for (int i2 = 0; i2 < 4; ++i2) {
        const int r = i2 + (i2 >> 1);        // {0,1,3,4}
        const int lr = ty + r;
        LOADW(lr)
        COMPW()
    }

    float4 o0, o1;
    float* o0a = (float*)&o0;
    float* o1a = (float*)&o1;
#pragma unroll
    for (int j = 0; j < 4; ++j) {
        const float rcp = 1.f / den[j];
        // mimic the reference's fp16 round-trip
        o0a[j] = __half2float(__float2half(num0[j] * rcp));
        o1a[j] = __half2float(__float2half(num1[j] * rcp));
    }
    const int ctr = (gy0 + ty) * W_ + gx0 + 4 * tx;
    *(float4*)(on + ctr) = o0;
    *(float4*)(on + HW + ctr) = o1;
}

extern "C" void kernel_launch(void* const* d_in, const int* in_sizes, int n_in,
                              void* d_out, int out_size, void* d_ws, size_t ws_size,
                              hipStream_t stream) {
    const float* t = (const float*)d_in[0];
    const float* v = (const float*)d_in[1];
    float* out = (float*)d_out;

    // 10 x-tiles * 90 y-tiles * 2 images = 1800 blocks of 256 (XCD-swizzled)
    jbf_h2<<<1800, 256, 0, stream>>>(t, v, out);
}